// Round 7
// baseline (741.377 us; speedup 1.0000x reference)
//
#include <hip/hip_runtime.h>

#define SEQ 1024
#define BATCH 512
#define NTAGS 64
#define LOGD 4.158883083f   // log(64): per-step damp folded into exp(em)

typedef _Float16 v2h  __attribute__((ext_vector_type(2)));
typedef _Float16 v8h  __attribute__((ext_vector_type(8)));
typedef float    f32x4 __attribute__((ext_vector_type(4)));
typedef unsigned uv4  __attribute__((ext_vector_type(4)));

__device__ __forceinline__ void swap32pair(unsigned x, unsigned& a, unsigned& b) {
#if __has_builtin(__builtin_amdgcn_permlane32_swap)
    auto r = __builtin_amdgcn_permlane32_swap(x, x, false, false);
    a = (unsigned)r[0]; b = (unsigned)r[1];
#else
    a = x; b = (unsigned)__shfl_xor((int)x, 32);
#endif
}

__device__ __forceinline__ void swap16pair(unsigned x, unsigned& a, unsigned& b) {
#if __has_builtin(__builtin_amdgcn_permlane16_swap)
    auto r = __builtin_amdgcn_permlane16_swap(x, x, false, false);
    a = (unsigned)r[0]; b = (unsigned)r[1];
#else
    a = x; b = (unsigned)__shfl_xor((int)x, 16);
#endif
}

__device__ __forceinline__ unsigned pkrtz(float lo, float hi) {
#if __has_builtin(__builtin_amdgcn_cvt_pkrtz)
    auto p = __builtin_amdgcn_cvt_pkrtz(lo, hi);
    return __builtin_bit_cast(unsigned, p);
#else
    v2h t; t.x = (_Float16)lo; t.y = (_Float16)hi;
    return __builtin_bit_cast(unsigned, t);
#endif
}

// MFMA-batched CRF scan: 16 chains per wave (chain = lane&15 column).
// State P[m][r] (f32) at lane (g=l>>4, c=l&15) holds state-row
// sigma = m*16 + 4g + r of chain b0+c.  Step:
//   B-frag(kt) words = {pk(P[2kt] r01), pk(P[2kt] r23), pk(P[2kt+1] r01), pk(P[2kt+1] r23)}
//   D[m] = mfma16x16x32_f16(A[m][0], B0, 0); D[m] = mfma(A[m][1], B1, D[m])
// The A fragments are loaded so that hardware k-slot (kt, g, e) carries true
// input row (2kt+(e>>2))*16 + 4g + (e&3) — making C-layout == next-B-layout
// with ZERO cross-lane data movement (chain stays in lane&15 both sides).
// Ragged lengths handled by per-column cndmask freeze; renorm every 4 steps
// via order-agnostic pair-sums (swap16+swap32, commutative adds).
__global__ __launch_bounds__(64, 1)
void scan_kernel(const float* __restrict__ em,
                 const int* __restrict__ mask,
                 const float* __restrict__ startT,
                 const float* __restrict__ endT,
                 const float* __restrict__ trans,
                 float* __restrict__ beta_f, float* __restrict__ Mf,
                 float* __restrict__ gma,    float* __restrict__ Mb,
                 int* __restrict__ Lw)
{
    const int  blk = blockIdx.x;
    const bool isF = blk < (BATCH / 16);
    const int  b0  = (isF ? blk : blk - BATCH / 16) * 16;
    const int  l   = threadIdx.x;
    const int  c   = l & 15;
    const int  g   = l >> 4;

    // ---- chain lengths: lane (g,c) sums a quarter of chain c's mask column
    int ls = 0;
#pragma unroll 8
    for (int i = 0; i < 256; ++i)
        ls += mask[(g * 256 + i) * BATCH + b0 + c];
    {
        unsigned a, b;
        swap16pair((unsigned)ls, a, b); ls = (int)(a + b);   // + partner16
        swap32pair((unsigned)ls, a, b); ls = (int)(a + b);   // + partner32
    }
    const int Lc   = ls;
    const int Lact = isF ? min(Lc - 1, 511) : (Lc - 1);

    // ---- A fragments: A[m][kt], elem e at lane l supplies
    //      out-row = m*16 + (l&15), in-row = (2kt+(e>>2))*16 + 4*(l>>4) + (e&3)
    //      fwd: Mhat[out][in] = exp(T[in][out]);  bwd: exp(T[out][in])
    v8h Af[4][2];
#pragma unroll
    for (int m = 0; m < 4; ++m) {
#pragma unroll
        for (int kt = 0; kt < 2; ++kt) {
            v8h a;
#pragma unroll
            for (int e = 0; e < 8; ++e) {
                int srow = (2 * kt + (e >> 2)) * 16 + 4 * g + (e & 3);
                int orow = m * 16 + c;
                float tv = isF ? trans[srow * NTAGS + orow]
                               : trans[orow * NTAGS + srow];
                a[e] = (_Float16)__expf(tv);
            }
            Af[m][kt] = a;
        }
    }

    // ---- state init
    f32x4 P[4];
    float M;
    if (isF) {
        float m0 = startT[0] + em[(size_t)(b0 + c) * NTAGS];   // row-0 anchor
#pragma unroll
        for (int m = 0; m < 4; ++m) {
            f32x4 p;
#pragma unroll
            for (int r = 0; r < 4; ++r) {
                int row = m * 16 + 4 * g + r;
                p[r] = __expf(startT[row] + em[(size_t)(b0 + c) * NTAGS + row] - m0);
            }
            P[m] = p;
        }
        M = m0;
    } else {
#pragma unroll
        for (int m = 0; m < 4; ++m) {
            f32x4 p;
#pragma unroll
            for (int r = 0; r < 4; ++r) {
                int row = m * 16 + 4 * g + r;
                p[r] = __expf(endT[row]);
            }
            P[m] = p;
        }
        M = 0.0f;
    }

#define TSTEP(IT, U) (isF ? (4 * (IT) + (U) + 1) : (1023 - (4 * (IT) + (U))))
#define EM_LD(T, MM) (*reinterpret_cast<const f32x4*>( \
        &em[((size_t)(T) * BATCH + b0 + c) * NTAGS + (MM) * 16 + 4 * g]))

    // ---- em double-buffer: consume curE (loaded 1 iter ago), prefetch nxtE
    f32x4 curE[4][4], nxtE[4][4];   // [u][m]
#pragma unroll
    for (int u = 0; u < 4; ++u)
#pragma unroll
        for (int m = 0; m < 4; ++m) {
            curE[u][m] = EM_LD(TSTEP(0, u), m);
            nxtE[u][m] = EM_LD(TSTEP(1, u), m);
        }

    const f32x4 z4 = {0.f, 0.f, 0.f, 0.f};

    for (int it = 0; it < 128; ++it) {
#pragma unroll
        for (int u = 0; u < 4; ++u) {
            const int  t   = TSTEP(it, u);
            const bool act = (t <= Lact);

            f32x4 e4[4];
#pragma unroll
            for (int m = 0; m < 4; ++m) {
                f32x4 x = curE[u][m], y;
#pragma unroll
                for (int r = 0; r < 4; ++r) y[r] = __expf(x[r] - LOGD);
                e4[m] = y;
            }

            // B operand: fwd uses P directly (e applied post-matrix);
            // bwd pre-multiplies by e (matches R0 recurrences exactly).
            f32x4 T4[4];
#pragma unroll
            for (int m = 0; m < 4; ++m)
                T4[m] = isF ? P[m] : (P[m] * e4[m]);

            unsigned pk0[4], pk1[4];
#pragma unroll
            for (int m = 0; m < 4; ++m) {
                pk0[m] = pkrtz(T4[m][0], T4[m][1]);
                pk1[m] = pkrtz(T4[m][2], T4[m][3]);
            }
            uv4 bw0 = {pk0[0], pk1[0], pk0[1], pk1[1]};
            uv4 bw1 = {pk0[2], pk1[2], pk0[3], pk1[3]};
            v8h B0 = __builtin_bit_cast(v8h, bw0);
            v8h B1 = __builtin_bit_cast(v8h, bw1);

#pragma unroll
            for (int m = 0; m < 4; ++m) {
                f32x4 d = __builtin_amdgcn_mfma_f32_16x16x32_f16(Af[m][0], B0, z4, 0, 0, 0);
                d = __builtin_amdgcn_mfma_f32_16x16x32_f16(Af[m][1], B1, d, 0, 0, 0);
                f32x4 pn;
#pragma unroll
                for (int r = 0; r < 4; ++r)
                    pn[r] = isF ? (d[r] * e4[m][r]) : d[r];
#pragma unroll
                for (int r = 0; r < 4; ++r)
                    P[m][r] = act ? pn[r] : P[m][r];
            }
        }

        // ---- renorm every 4 steps: r = 16 * sum_g P[0][0] (col-uniform, >0)
        {
            unsigned a, b;
            float v = P[0][0];
            swap16pair(__float_as_uint(v), a, b);
            float s1 = __uint_as_float(a) + __uint_as_float(b);
            swap32pair(__float_as_uint(s1), a, b);
            float rr = (__uint_as_float(a) + __uint_as_float(b)) * 16.0f;
            float ri = 1.0f / rr;
            M += __logf(rr);
#pragma unroll
            for (int m = 0; m < 4; ++m) P[m] *= ri;
        }

        // ---- rotate prefetch (loads for it+2: fwd t<=520, bwd tt>=504 — in range)
#pragma unroll
        for (int u = 0; u < 4; ++u)
#pragma unroll
            for (int m = 0; m < 4; ++m) {
                curE[u][m] = nxtE[u][m];
                nxtE[u][m] = EM_LD(TSTEP(it + 2, u), m);
            }
    }
#undef TSTEP
#undef EM_LD

    // ---- stores (row-major per batch; join is permutation-invariant anyway,
    //      and fwd/bwd use the same labeling so the dot matches pointwise)
    if (isF) {
#pragma unroll
        for (int m = 0; m < 4; ++m)
            *reinterpret_cast<f32x4*>(&beta_f[(size_t)(b0 + c) * NTAGS + m * 16 + 4 * g]) = P[m];
        if (g == 0) {
            Mf[b0 + c] = fmaf((float)Lact, LOGD, M);
            Lw[b0 + c] = Lc;
        }
    } else {
#pragma unroll
        for (int m = 0; m < 4; ++m)
            *reinterpret_cast<f32x4*>(&gma[(size_t)(b0 + c) * NTAGS + m * 16 + 4 * g]) = P[m];
        if (g == 0) {
            int nb = max(Lc - 512, 0);
            Mb[b0 + c] = fmaf((float)nb, LOGD, M);
        }
    }
}

// Join: per chain, numerator (fully parallel masked gather-sum) + the
// midpoint dot Z = log(sum_j beta_j * B_j) + Mf + Mb; accumulate llh.
// (Verbatim from the verified R0 kernel.)
__global__ __launch_bounds__(64)
void join_kernel(const float* __restrict__ em,
                 const int* __restrict__ tags,
                 const float* __restrict__ startT,
                 const float* __restrict__ endT,
                 const float* __restrict__ trans,
                 const float* __restrict__ beta_f, const float* __restrict__ Mf,
                 const float* __restrict__ gma,    const float* __restrict__ Mb,
                 const int* __restrict__ Lw,
                 float* __restrict__ out)
{
    const int b = blockIdx.x;
    const int j = threadIdx.x;

    __shared__ float tr_sh[NTAGS * NTAGS];
#pragma unroll
    for (int i = 0; i < NTAGS; ++i)
        tr_sh[i * NTAGS + j] = trans[i * NTAGS + j];
    __syncthreads();

    const int L = Lw[b];

    float np = 0.0f;
#pragma unroll
    for (int k = 0; k < SEQ / 64; ++k) {
        int t = k * 64 + j;
        if (t >= 1 && t < L) {
            int ct = tags[t * BATCH + b];
            int pt = tags[(t - 1) * BATCH + b];
            np += tr_sh[pt * NTAGS + ct] + em[((size_t)t * BATCH + b) * NTAGS + ct];
        }
    }
    if (j == 0) {
        int t0 = tags[b];
        np += startT[t0] + em[(size_t)b * NTAGS + t0]
            + endT[tags[(size_t)(L - 1) * BATCH + b]];
    }

    float p = beta_f[b * NTAGS + j] * gma[b * NTAGS + j];

#pragma unroll
    for (int off = 32; off > 0; off >>= 1) {
        np += __shfl_xor(np, off);
        p  += __shfl_xor(p,  off);
    }

    if (j == 0) {
        float denom = __logf(p) + Mf[b] + Mb[b];
        atomicAdd(out, np - denom);
    }
}

extern "C" void kernel_launch(void* const* d_in, const int* in_sizes, int n_in,
                              void* d_out, int out_size, void* d_ws, size_t ws_size,
                              hipStream_t stream)
{
    const float* em     = (const float*)d_in[0];
    const int*   tags   = (const int*)d_in[1];
    const int*   mask   = (const int*)d_in[2];
    const float* startT = (const float*)d_in[3];
    const float* endT   = (const float*)d_in[4];
    const float* trans  = (const float*)d_in[5];
    float*       out    = (float*)d_out;

    float* beta_f = (float*)d_ws;                 // 512*64
    float* Mf     = beta_f + BATCH * NTAGS;       // 512
    float* gma    = Mf + BATCH;                   // 512*64
    float* Mb     = gma + BATCH * NTAGS;          // 512
    int*   Lw     = (int*)(Mb + BATCH);           // 512

    hipMemsetAsync(out, 0, sizeof(float) * out_size, stream);
    scan_kernel<<<2 * (BATCH / 16), 64, 0, stream>>>(em, mask, startT, endT, trans,
                                                     beta_f, Mf, gma, Mb, Lw);
    join_kernel<<<BATCH, 64, 0, stream>>>(em, tags, startT, endT, trans,
                                          beta_f, Mf, gma, Mb, Lw, out);
}

// Round 8
// 675.699 us; speedup vs baseline: 1.0972x; 1.0972x over previous
//
#include <hip/hip_runtime.h>

#define SEQ 1024
#define BATCH 512
#define NTAGS 64
#define LOGD 4.158883083f   // log(64): per-step damp folded into exp(em)

typedef _Float16 v2h  __attribute__((ext_vector_type(2)));
typedef _Float16 v8h  __attribute__((ext_vector_type(8)));
typedef float    f32x4 __attribute__((ext_vector_type(4)));
typedef unsigned uv4  __attribute__((ext_vector_type(4)));

__device__ __forceinline__ void swap32pair(unsigned x, unsigned& a, unsigned& b) {
#if __has_builtin(__builtin_amdgcn_permlane32_swap)
    auto r = __builtin_amdgcn_permlane32_swap(x, x, false, false);
    a = (unsigned)r[0]; b = (unsigned)r[1];
#else
    a = x; b = (unsigned)__shfl_xor((int)x, 32);
#endif
}

__device__ __forceinline__ void swap16pair(unsigned x, unsigned& a, unsigned& b) {
#if __has_builtin(__builtin_amdgcn_permlane16_swap)
    auto r = __builtin_amdgcn_permlane16_swap(x, x, false, false);
    a = (unsigned)r[0]; b = (unsigned)r[1];
#else
    a = x; b = (unsigned)__shfl_xor((int)x, 16);
#endif
}

__device__ __forceinline__ unsigned pkrtz(float lo, float hi) {
#if __has_builtin(__builtin_amdgcn_cvt_pkrtz)
    auto p = __builtin_amdgcn_cvt_pkrtz(lo, hi);
    return __builtin_bit_cast(unsigned, p);
#else
    v2h t; t.x = (_Float16)lo; t.y = (_Float16)hi;
    return __builtin_bit_cast(unsigned, t);
#endif
}

// MFMA-batched CRF scan: 16 chains per wave (chain = lane&15 column).
// Layout verified in R7 (absmax=0). R8 change: ALL per-iteration state in
// NAMED registers (R7's indexed f32x4 arrays spilled to scratch: VGPR=68,
// ~11K cyc/iter, all pipes <2% busy — rule #20). Software pipeline: each
// step consumes its em slot then reloads it for step t+4 (~1000 cyc ahead).
__global__ __launch_bounds__(64, 1)
void scan_kernel(const float* __restrict__ em,
                 const int* __restrict__ mask,
                 const float* __restrict__ startT,
                 const float* __restrict__ endT,
                 const float* __restrict__ trans,
                 float* __restrict__ beta_f, float* __restrict__ Mf,
                 float* __restrict__ gma,    float* __restrict__ Mb,
                 int* __restrict__ Lw)
{
    const int  blk = blockIdx.x;
    const bool isF = blk < (BATCH / 16);
    const int  b0  = (isF ? blk : blk - BATCH / 16) * 16;
    const int  l   = threadIdx.x;
    const int  c   = l & 15;
    const int  g   = l >> 4;

    // ---- chain lengths: lane (g,c) sums a quarter of chain c's mask column
    int ls = 0;
#pragma unroll 8
    for (int i = 0; i < 256; ++i)
        ls += mask[(g * 256 + i) * BATCH + b0 + c];
    {
        unsigned a, b;
        swap16pair((unsigned)ls, a, b); ls = (int)(a + b);
        swap32pair((unsigned)ls, a, b); ls = (int)(a + b);
    }
    const int Lc   = ls;
    const int Lact = isF ? min(Lc - 1, 511) : (Lc - 1);

    // ---- A fragments (named): A<m><kt>, elem e at lane l supplies
    //      out-row = m*16 + c, in-row = (2kt+(e>>2))*16 + 4g + (e&3)
    v8h A00, A01, A10, A11, A20, A21, A30, A31;
#define AINIT(VAR, MM, KT)                                                 \
    {                                                                      \
        v8h a_;                                                            \
        _Pragma("unroll")                                                  \
        for (int e = 0; e < 8; ++e) {                                      \
            int srow = (2 * (KT) + (e >> 2)) * 16 + 4 * g + (e & 3);       \
            int orow = (MM) * 16 + c;                                      \
            float tv = isF ? trans[srow * NTAGS + orow]                    \
                           : trans[orow * NTAGS + srow];                   \
            a_[e] = (_Float16)__expf(tv);                                  \
        }                                                                  \
        VAR = a_;                                                          \
    }
    AINIT(A00, 0, 0) AINIT(A01, 0, 1) AINIT(A10, 1, 0) AINIT(A11, 1, 1)
    AINIT(A20, 2, 0) AINIT(A21, 2, 1) AINIT(A30, 3, 0) AINIT(A31, 3, 1)
#undef AINIT

    // ---- state init (named)
    f32x4 P0, P1, P2, P3;
    float M;
#define PINIT(VAR, MM)                                                             \
    {                                                                              \
        f32x4 p_;                                                                  \
        _Pragma("unroll")                                                          \
        for (int r = 0; r < 4; ++r) {                                              \
            int row = (MM) * 16 + 4 * g + r;                                       \
            p_[r] = isF ? __expf(startT[row] + em[(size_t)(b0 + c) * NTAGS + row] - M) \
                        : __expf(endT[row]);                                       \
        }                                                                          \
        VAR = p_;                                                                  \
    }
    M = isF ? (startT[0] + em[(size_t)(b0 + c) * NTAGS]) : 0.0f;   // row-0 anchor
    PINIT(P0, 0) PINIT(P1, 1) PINIT(P2, 2) PINIT(P3, 3)
#undef PINIT

#define EM_LD(T, MM) (*reinterpret_cast<const f32x4*>( \
        &em[((size_t)(T) * BATCH + b0 + c) * NTAGS + (MM) * 16 + 4 * g]))

    // ---- em slots (named): E<u><m> holds step u's 4 values for quadrant m
    f32x4 E00, E01, E02, E03, E10, E11, E12, E13,
          E20, E21, E22, E23, E30, E31, E32, E33;
    {
        const int ti0 = isF ? 1 : 1023;
        const int d_  = isF ? 1 : -1;
        E00 = EM_LD(ti0,        0); E01 = EM_LD(ti0,        1);
        E02 = EM_LD(ti0,        2); E03 = EM_LD(ti0,        3);
        E10 = EM_LD(ti0 + d_,   0); E11 = EM_LD(ti0 + d_,   1);
        E12 = EM_LD(ti0 + d_,   2); E13 = EM_LD(ti0 + d_,   3);
        E20 = EM_LD(ti0 + 2*d_, 0); E21 = EM_LD(ti0 + 2*d_, 1);
        E22 = EM_LD(ti0 + 2*d_, 2); E23 = EM_LD(ti0 + 2*d_, 3);
        E30 = EM_LD(ti0 + 3*d_, 0); E31 = EM_LD(ti0 + 3*d_, 1);
        E32 = EM_LD(ti0 + 3*d_, 2); E33 = EM_LD(ti0 + 3*d_, 3);
    }

    const f32x4 z4 = {0.f, 0.f, 0.f, 0.f};

// One recurrence step at time TCUR using slots EA..ED (m=0..3); after
// consuming them into e-vectors, reload the SAME slots for time TPRE
// (= TCUR +/- 4): ~1 iteration (~1000 cyc) of load lead time.
#define STEP(EA, EB, EC, ED, TCUR, TPRE)                                        \
    {                                                                           \
        const bool act_ = (TCUR) <= Lact;                                       \
        f32x4 ea_, eb_, ec_, ed_;                                               \
        ea_[0] = __expf(EA[0] - LOGD); ea_[1] = __expf(EA[1] - LOGD);           \
        ea_[2] = __expf(EA[2] - LOGD); ea_[3] = __expf(EA[3] - LOGD);           \
        eb_[0] = __expf(EB[0] - LOGD); eb_[1] = __expf(EB[1] - LOGD);           \
        eb_[2] = __expf(EB[2] - LOGD); eb_[3] = __expf(EB[3] - LOGD);           \
        ec_[0] = __expf(EC[0] - LOGD); ec_[1] = __expf(EC[1] - LOGD);           \
        ec_[2] = __expf(EC[2] - LOGD); ec_[3] = __expf(EC[3] - LOGD);           \
        ed_[0] = __expf(ED[0] - LOGD); ed_[1] = __expf(ED[1] - LOGD);           \
        ed_[2] = __expf(ED[2] - LOGD); ed_[3] = __expf(ED[3] - LOGD);           \
        EA = EM_LD(TPRE, 0); EB = EM_LD(TPRE, 1);                               \
        EC = EM_LD(TPRE, 2); ED = EM_LD(TPRE, 3);                               \
        f32x4 t0_ = isF ? P0 : (P0 * ea_);                                      \
        f32x4 t1_ = isF ? P1 : (P1 * eb_);                                      \
        f32x4 t2_ = isF ? P2 : (P2 * ec_);                                      \
        f32x4 t3_ = isF ? P3 : (P3 * ed_);                                      \
        unsigned q00_ = pkrtz(t0_[0], t0_[1]), q01_ = pkrtz(t0_[2], t0_[3]);    \
        unsigned q10_ = pkrtz(t1_[0], t1_[1]), q11_ = pkrtz(t1_[2], t1_[3]);    \
        unsigned q20_ = pkrtz(t2_[0], t2_[1]), q21_ = pkrtz(t2_[2], t2_[3]);    \
        unsigned q30_ = pkrtz(t3_[0], t3_[1]), q31_ = pkrtz(t3_[2], t3_[3]);    \
        uv4 bw0_ = {q00_, q01_, q10_, q11_};                                    \
        uv4 bw1_ = {q20_, q21_, q30_, q31_};                                    \
        v8h B0_ = __builtin_bit_cast(v8h, bw0_);                                \
        v8h B1_ = __builtin_bit_cast(v8h, bw1_);                                \
        f32x4 d0_ = __builtin_amdgcn_mfma_f32_16x16x32_f16(A00, B0_, z4, 0, 0, 0); \
        d0_ = __builtin_amdgcn_mfma_f32_16x16x32_f16(A01, B1_, d0_, 0, 0, 0);   \
        f32x4 d1_ = __builtin_amdgcn_mfma_f32_16x16x32_f16(A10, B0_, z4, 0, 0, 0); \
        d1_ = __builtin_amdgcn_mfma_f32_16x16x32_f16(A11, B1_, d1_, 0, 0, 0);   \
        f32x4 d2_ = __builtin_amdgcn_mfma_f32_16x16x32_f16(A20, B0_, z4, 0, 0, 0); \
        d2_ = __builtin_amdgcn_mfma_f32_16x16x32_f16(A21, B1_, d2_, 0, 0, 0);   \
        f32x4 d3_ = __builtin_amdgcn_mfma_f32_16x16x32_f16(A30, B0_, z4, 0, 0, 0); \
        d3_ = __builtin_amdgcn_mfma_f32_16x16x32_f16(A31, B1_, d3_, 0, 0, 0);   \
        P0 = act_ ? (isF ? (d0_ * ea_) : d0_) : P0;                             \
        P1 = act_ ? (isF ? (d1_ * eb_) : d1_) : P1;                             \
        P2 = act_ ? (isF ? (d2_ * ec_) : d2_) : P2;                             \
        P3 = act_ ? (isF ? (d3_ * ed_) : d3_) : P3;                             \
    }

    for (int it = 0; it < 128; ++it) {
        const int tb = isF ? (4 * it + 1) : (1023 - 4 * it);
        const int d_ = isF ? 1 : -1;
        STEP(E00, E01, E02, E03, tb,          tb + 4 * d_)
        STEP(E10, E11, E12, E13, tb + d_,     tb + 5 * d_)
        STEP(E20, E21, E22, E23, tb + 2 * d_, tb + 6 * d_)
        STEP(E30, E31, E32, E33, tb + 3 * d_, tb + 7 * d_)

        // renorm every 4 steps: rr = 16 * sum_g P0[0] (col-uniform, > 0)
        {
            unsigned a, b;
            swap16pair(__float_as_uint(P0[0]), a, b);
            float s1 = __uint_as_float(a) + __uint_as_float(b);
            swap32pair(__float_as_uint(s1), a, b);
            float rr = (__uint_as_float(a) + __uint_as_float(b)) * 16.0f;
            float ri = 1.0f / rr;
            M += __logf(rr);
            P0 *= ri; P1 *= ri; P2 *= ri; P3 *= ri;
        }
    }
#undef STEP
#undef EM_LD

    // ---- stores
    if (isF) {
        *reinterpret_cast<f32x4*>(&beta_f[(size_t)(b0 + c) * NTAGS +  0 + 4 * g]) = P0;
        *reinterpret_cast<f32x4*>(&beta_f[(size_t)(b0 + c) * NTAGS + 16 + 4 * g]) = P1;
        *reinterpret_cast<f32x4*>(&beta_f[(size_t)(b0 + c) * NTAGS + 32 + 4 * g]) = P2;
        *reinterpret_cast<f32x4*>(&beta_f[(size_t)(b0 + c) * NTAGS + 48 + 4 * g]) = P3;
        if (g == 0) {
            Mf[b0 + c] = fmaf((float)Lact, LOGD, M);
            Lw[b0 + c] = Lc;
        }
    } else {
        *reinterpret_cast<f32x4*>(&gma[(size_t)(b0 + c) * NTAGS +  0 + 4 * g]) = P0;
        *reinterpret_cast<f32x4*>(&gma[(size_t)(b0 + c) * NTAGS + 16 + 4 * g]) = P1;
        *reinterpret_cast<f32x4*>(&gma[(size_t)(b0 + c) * NTAGS + 32 + 4 * g]) = P2;
        *reinterpret_cast<f32x4*>(&gma[(size_t)(b0 + c) * NTAGS + 48 + 4 * g]) = P3;
        if (g == 0) {
            int nb = max(Lc - 512, 0);
            Mb[b0 + c] = fmaf((float)nb, LOGD, M);
        }
    }
}

// Join: per chain, numerator (fully parallel masked gather-sum) + the
// midpoint dot Z = log(sum_j beta_j * B_j) + Mf + Mb; accumulate llh.
// (Verbatim from the verified R0 kernel.)
__global__ __launch_bounds__(64)
void join_kernel(const float* __restrict__ em,
                 const int* __restrict__ tags,
                 const float* __restrict__ startT,
                 const float* __restrict__ endT,
                 const float* __restrict__ trans,
                 const float* __restrict__ beta_f, const float* __restrict__ Mf,
                 const float* __restrict__ gma,    const float* __restrict__ Mb,
                 const int* __restrict__ Lw,
                 float* __restrict__ out)
{
    const int b = blockIdx.x;
    const int j = threadIdx.x;

    __shared__ float tr_sh[NTAGS * NTAGS];
#pragma unroll
    for (int i = 0; i < NTAGS; ++i)
        tr_sh[i * NTAGS + j] = trans[i * NTAGS + j];
    __syncthreads();

    const int L = Lw[b];

    float np = 0.0f;
#pragma unroll
    for (int k = 0; k < SEQ / 64; ++k) {
        int t = k * 64 + j;
        if (t >= 1 && t < L) {
            int ct = tags[t * BATCH + b];
            int pt = tags[(t - 1) * BATCH + b];
            np += tr_sh[pt * NTAGS + ct] + em[((size_t)t * BATCH + b) * NTAGS + ct];
        }
    }
    if (j == 0) {
        int t0 = tags[b];
        np += startT[t0] + em[(size_t)b * NTAGS + t0]
            + endT[tags[(size_t)(L - 1) * BATCH + b]];
    }

    float p = beta_f[b * NTAGS + j] * gma[b * NTAGS + j];

#pragma unroll
    for (int off = 32; off > 0; off >>= 1) {
        np += __shfl_xor(np, off);
        p  += __shfl_xor(p,  off);
    }

    if (j == 0) {
        float denom = __logf(p) + Mf[b] + Mb[b];
        atomicAdd(out, np - denom);
    }
}

extern "C" void kernel_launch(void* const* d_in, const int* in_sizes, int n_in,
                              void* d_out, int out_size, void* d_ws, size_t ws_size,
                              hipStream_t stream)
{
    const float* em     = (const float*)d_in[0];
    const int*   tags   = (const int*)d_in[1];
    const int*   mask   = (const int*)d_in[2];
    const float* startT = (const float*)d_in[3];
    const float* endT   = (const float*)d_in[4];
    const float* trans  = (const float*)d_in[5];
    float*       out    = (float*)d_out;

    float* beta_f = (float*)d_ws;                 // 512*64
    float* Mf     = beta_f + BATCH * NTAGS;       // 512
    float* gma    = Mf + BATCH;                   // 512*64
    float* Mb     = gma + BATCH * NTAGS;          // 512
    int*   Lw     = (int*)(Mb + BATCH);           // 512

    hipMemsetAsync(out, 0, sizeof(float) * out_size, stream);
    scan_kernel<<<2 * (BATCH / 16), 64, 0, stream>>>(em, mask, startT, endT, trans,
                                                     beta_f, Mf, gma, Mb, Lw);
    join_kernel<<<BATCH, 64, 0, stream>>>(em, tags, startT, endT, trans,
                                          beta_f, Mf, gma, Mb, Lw, out);
}

// Round 9
// 375.194 us; speedup vs baseline: 1.9760x; 1.8009x over previous
//
#include <hip/hip_runtime.h>

#define SEQ 1024
#define BATCH 512
#define NTAGS 64
#define LOGD 4.158883083f   // log(64): per-step damp folded into exp(em)
#define STRIDE_T (BATCH * NTAGS)   // floats per time step (32768)

typedef _Float16 v2h  __attribute__((ext_vector_type(2)));
typedef _Float16 v8h  __attribute__((ext_vector_type(8)));
typedef float    f32x4 __attribute__((ext_vector_type(4)));
typedef unsigned uv4  __attribute__((ext_vector_type(4)));

__device__ __forceinline__ void swap32pair(unsigned x, unsigned& a, unsigned& b) {
#if __has_builtin(__builtin_amdgcn_permlane32_swap)
    auto r = __builtin_amdgcn_permlane32_swap(x, x, false, false);
    a = (unsigned)r[0]; b = (unsigned)r[1];
#else
    a = x; b = (unsigned)__shfl_xor((int)x, 32);
#endif
}

__device__ __forceinline__ void swap16pair(unsigned x, unsigned& a, unsigned& b) {
#if __has_builtin(__builtin_amdgcn_permlane16_swap)
    auto r = __builtin_amdgcn_permlane16_swap(x, x, false, false);
    a = (unsigned)r[0]; b = (unsigned)r[1];
#else
    a = x; b = (unsigned)__shfl_xor((int)x, 16);
#endif
}

__device__ __forceinline__ unsigned pkrtz(float lo, float hi) {
#if __has_builtin(__builtin_amdgcn_cvt_pkrtz)
    auto p = __builtin_amdgcn_cvt_pkrtz(lo, hi);
    return __builtin_bit_cast(unsigned, p);
#else
    v2h t; t.x = (_Float16)lo; t.y = (_Float16)hi;
    return __builtin_bit_cast(unsigned, t);
#endif
}

// Pinned load: asm volatile can't be sunk by the scheduler (R7/R8 lesson:
// plain C++ loads get sunk to their uses, putting full memory latency on
// the serial critical path — VGPR=68 with no spill traffic proved it).
#define GLD(DST, PTR, OFFB)                                                \
    asm volatile("global_load_dwordx4 %0, %1, off offset:%2"               \
                 : "=v"(DST) : "v"(PTR), "i"(OFFB))

// Counted wait (T4 discipline, single-wave form): drain the CONSUMED set
// (issued one half ago) while the 16 loads of the other set stay in
// flight. "+v" ties re-define the consumed regs so no use can be
// scheduled above the wait (rule #18); sched_barrier seals it.
#define WAIT16(X0,X1,X2,X3,X4,X5,X6,X7,X8,X9,X10,X11,X12,X13,X14,X15)      \
    asm volatile("s_waitcnt vmcnt(16)"                                     \
        : "+v"(X0), "+v"(X1), "+v"(X2),  "+v"(X3),                         \
          "+v"(X4), "+v"(X5), "+v"(X6),  "+v"(X7),                         \
          "+v"(X8), "+v"(X9), "+v"(X10), "+v"(X11),                        \
          "+v"(X12),"+v"(X13),"+v"(X14), "+v"(X15));                       \
    __builtin_amdgcn_sched_barrier(0)

// 16 loads for one 4-step half: set S (E or F), pointers p0..p3 = step
// u's per-lane base, quadrant m at byte offset m*64.
#define LOADSET(S, P0, P1, P2, P3)                                         \
    GLD(S##00, P0, 0); GLD(S##01, P0, 64); GLD(S##02, P0, 128); GLD(S##03, P0, 192); \
    GLD(S##10, P1, 0); GLD(S##11, P1, 64); GLD(S##12, P1, 128); GLD(S##13, P1, 192); \
    GLD(S##20, P2, 0); GLD(S##21, P2, 64); GLD(S##22, P2, 128); GLD(S##23, P2, 192); \
    GLD(S##30, P3, 0); GLD(S##31, P3, 64); GLD(S##32, P3, 128); GLD(S##33, P3, 192); \
    __builtin_amdgcn_sched_barrier(0)

// MFMA-batched CRF scan: 16 chains per wave (chain = lane&15 column).
// Algorithm/layout verified in R7/R8 (absmax=0). R9: hand-pinned load
// pipeline (asm loads + counted vmcnt), compute untouched in C++.
__global__ __launch_bounds__(64, 1)
void scan_kernel(const float* __restrict__ em,
                 const int* __restrict__ mask,
                 const float* __restrict__ startT,
                 const float* __restrict__ endT,
                 const float* __restrict__ trans,
                 float* __restrict__ beta_f, float* __restrict__ Mf,
                 float* __restrict__ gma,    float* __restrict__ Mb,
                 int* __restrict__ Lw)
{
    const int  blk = blockIdx.x;
    const bool isF = blk < (BATCH / 16);
    const int  b0  = (isF ? blk : blk - BATCH / 16) * 16;
    const int  l   = threadIdx.x;
    const int  c   = l & 15;
    const int  g   = l >> 4;

    // ---- chain lengths: lane (g,c) sums a quarter of chain c's mask column
    int ls = 0;
#pragma unroll 8
    for (int i = 0; i < 256; ++i)
        ls += mask[(g * 256 + i) * BATCH + b0 + c];
    {
        unsigned a, b;
        swap16pair((unsigned)ls, a, b); ls = (int)(a + b);
        swap32pair((unsigned)ls, a, b); ls = (int)(a + b);
    }
    const int Lc    = ls;
    const int LactF = min(Lc - 1, 511);   // fwd: step s active iff s < LactF
    const int sMinB = 1024 - Lc;          // bwd: step s active iff s >= sMinB

    // ---- A fragments (named): out-row = m*16 + c, in-row = (2kt+(e>>2))*16 + 4g + (e&3)
    v8h A00, A01, A10, A11, A20, A21, A30, A31;
#define AINIT(VAR, MM, KT)                                                 \
    {                                                                      \
        v8h a_;                                                            \
        _Pragma("unroll")                                                  \
        for (int e = 0; e < 8; ++e) {                                      \
            int srow = (2 * (KT) + (e >> 2)) * 16 + 4 * g + (e & 3);       \
            int orow = (MM) * 16 + c;                                      \
            float tv = isF ? trans[srow * NTAGS + orow]                    \
                           : trans[orow * NTAGS + srow];                   \
            a_[e] = (_Float16)__expf(tv);                                  \
        }                                                                  \
        VAR = a_;                                                          \
    }
    AINIT(A00, 0, 0) AINIT(A01, 0, 1) AINIT(A10, 1, 0) AINIT(A11, 1, 1)
    AINIT(A20, 2, 0) AINIT(A21, 2, 1) AINIT(A30, 3, 0) AINIT(A31, 3, 1)
#undef AINIT

    // ---- state init (named)
    f32x4 P0, P1, P2, P3;
    float M;
#define PINIT(VAR, MM)                                                             \
    {                                                                              \
        f32x4 p_;                                                                  \
        _Pragma("unroll")                                                          \
        for (int r = 0; r < 4; ++r) {                                              \
            int row = (MM) * 16 + 4 * g + r;                                       \
            p_[r] = isF ? __expf(startT[row] + em[(size_t)(b0 + c) * NTAGS + row] - M) \
                        : __expf(endT[row]);                                       \
        }                                                                          \
        VAR = p_;                                                                  \
    }
    M = isF ? (startT[0] + em[(size_t)(b0 + c) * NTAGS]) : 0.0f;   // row-0 anchor
    PINIT(P0, 0) PINIT(P1, 1) PINIT(P2, 2) PINIT(P3, 3)
#undef PINIT

    // ---- per-lane em pointers: step s -> t = isF ? s+1 : 1023-s
    const float* base_lane = em + (size_t)(b0 + c) * NTAGS + 4 * g;
    const ptrdiff_t adv = (ptrdiff_t)(isF ? 8 : -8) * STRIDE_T;
    const float* pE0 = base_lane + (ptrdiff_t)(isF ? 1 : 1023) * STRIDE_T;
    const float* pE1 = base_lane + (ptrdiff_t)(isF ? 2 : 1022) * STRIDE_T;
    const float* pE2 = base_lane + (ptrdiff_t)(isF ? 3 : 1021) * STRIDE_T;
    const float* pE3 = base_lane + (ptrdiff_t)(isF ? 4 : 1020) * STRIDE_T;
    const float* pF0 = base_lane + (ptrdiff_t)(isF ? 5 : 1019) * STRIDE_T;
    const float* pF1 = base_lane + (ptrdiff_t)(isF ? 6 : 1018) * STRIDE_T;
    const float* pF2 = base_lane + (ptrdiff_t)(isF ? 7 : 1017) * STRIDE_T;
    const float* pF3 = base_lane + (ptrdiff_t)(isF ? 8 : 1016) * STRIDE_T;

    f32x4 E00, E01, E02, E03, E10, E11, E12, E13,
          E20, E21, E22, E23, E30, E31, E32, E33;
    f32x4 F00, F01, F02, F03, F10, F11, F12, F13,
          F20, F21, F22, F23, F30, F31, F32, F33;

    // prologue: issue E (steps 0..3)
    LOADSET(E, pE0, pE1, pE2, pE3);
    pE0 += adv; pE1 += adv; pE2 += adv; pE3 += adv;

    const f32x4 z4 = {0.f, 0.f, 0.f, 0.f};

#define STEP(EA, EB, EC, ED, ACT)                                               \
    {                                                                           \
        const bool act_ = (ACT);                                                \
        f32x4 ea_, eb_, ec_, ed_;                                               \
        ea_[0] = __expf(EA[0] - LOGD); ea_[1] = __expf(EA[1] - LOGD);           \
        ea_[2] = __expf(EA[2] - LOGD); ea_[3] = __expf(EA[3] - LOGD);           \
        eb_[0] = __expf(EB[0] - LOGD); eb_[1] = __expf(EB[1] - LOGD);           \
        eb_[2] = __expf(EB[2] - LOGD); eb_[3] = __expf(EB[3] - LOGD);           \
        ec_[0] = __expf(EC[0] - LOGD); ec_[1] = __expf(EC[1] - LOGD);           \
        ec_[2] = __expf(EC[2] - LOGD); ec_[3] = __expf(EC[3] - LOGD);           \
        ed_[0] = __expf(ED[0] - LOGD); ed_[1] = __expf(ED[1] - LOGD);           \
        ed_[2] = __expf(ED[2] - LOGD); ed_[3] = __expf(ED[3] - LOGD);           \
        f32x4 t0_ = isF ? P0 : (P0 * ea_);                                      \
        f32x4 t1_ = isF ? P1 : (P1 * eb_);                                      \
        f32x4 t2_ = isF ? P2 : (P2 * ec_);                                      \
        f32x4 t3_ = isF ? P3 : (P3 * ed_);                                      \
        unsigned q00_ = pkrtz(t0_[0], t0_[1]), q01_ = pkrtz(t0_[2], t0_[3]);    \
        unsigned q10_ = pkrtz(t1_[0], t1_[1]), q11_ = pkrtz(t1_[2], t1_[3]);    \
        unsigned q20_ = pkrtz(t2_[0], t2_[1]), q21_ = pkrtz(t2_[2], t2_[3]);    \
        unsigned q30_ = pkrtz(t3_[0], t3_[1]), q31_ = pkrtz(t3_[2], t3_[3]);    \
        uv4 bw0_ = {q00_, q01_, q10_, q11_};                                    \
        uv4 bw1_ = {q20_, q21_, q30_, q31_};                                    \
        v8h B0_ = __builtin_bit_cast(v8h, bw0_);                                \
        v8h B1_ = __builtin_bit_cast(v8h, bw1_);                                \
        f32x4 d0_ = __builtin_amdgcn_mfma_f32_16x16x32_f16(A00, B0_, z4, 0, 0, 0); \
        d0_ = __builtin_amdgcn_mfma_f32_16x16x32_f16(A01, B1_, d0_, 0, 0, 0);   \
        f32x4 d1_ = __builtin_amdgcn_mfma_f32_16x16x32_f16(A10, B0_, z4, 0, 0, 0); \
        d1_ = __builtin_amdgcn_mfma_f32_16x16x32_f16(A11, B1_, d1_, 0, 0, 0);   \
        f32x4 d2_ = __builtin_amdgcn_mfma_f32_16x16x32_f16(A20, B0_, z4, 0, 0, 0); \
        d2_ = __builtin_amdgcn_mfma_f32_16x16x32_f16(A21, B1_, d2_, 0, 0, 0);   \
        f32x4 d3_ = __builtin_amdgcn_mfma_f32_16x16x32_f16(A30, B0_, z4, 0, 0, 0); \
        d3_ = __builtin_amdgcn_mfma_f32_16x16x32_f16(A31, B1_, d3_, 0, 0, 0);   \
        P0 = act_ ? (isF ? (d0_ * ea_) : d0_) : P0;                             \
        P1 = act_ ? (isF ? (d1_ * eb_) : d1_) : P1;                             \
        P2 = act_ ? (isF ? (d2_ * ec_) : d2_) : P2;                             \
        P3 = act_ ? (isF ? (d3_ * ed_) : d3_) : P3;                             \
    }

#define RENORM                                                             \
    {                                                                      \
        unsigned a_, b_;                                                   \
        swap16pair(__float_as_uint(P0[0]), a_, b_);                        \
        float s1_ = __uint_as_float(a_) + __uint_as_float(b_);             \
        swap32pair(__float_as_uint(s1_), a_, b_);                          \
        float rr_ = (__uint_as_float(a_) + __uint_as_float(b_)) * 16.0f;   \
        float ri_ = 1.0f / rr_;                                            \
        M += __logf(rr_);                                                  \
        P0 *= ri_; P1 *= ri_; P2 *= ri_; P3 *= ri_;                        \
    }

#define ACTOF(S) (isF ? ((S) < LactF) : ((S) >= sMinB))

    for (int k = 0; k < 64; ++k) {
        const int s0 = 8 * k;
        // ---- half A: prefetch F (steps s0+4..s0+7), compute E (s0..s0+3)
        LOADSET(F, pF0, pF1, pF2, pF3);
        pF0 += adv; pF1 += adv; pF2 += adv; pF3 += adv;
        WAIT16(E00, E01, E02, E03, E10, E11, E12, E13,
               E20, E21, E22, E23, E30, E31, E32, E33);
        STEP(E00, E01, E02, E03, ACTOF(s0 + 0))
        STEP(E10, E11, E12, E13, ACTOF(s0 + 1))
        STEP(E20, E21, E22, E23, ACTOF(s0 + 2))
        STEP(E30, E31, E32, E33, ACTOF(s0 + 3))
        RENORM
        // ---- half B: prefetch E (steps s0+8..s0+11), compute F (s0+4..s0+7)
        LOADSET(E, pE0, pE1, pE2, pE3);
        pE0 += adv; pE1 += adv; pE2 += adv; pE3 += adv;
        WAIT16(F00, F01, F02, F03, F10, F11, F12, F13,
               F20, F21, F22, F23, F30, F31, F32, F33);
        STEP(F00, F01, F02, F03, ACTOF(s0 + 4))
        STEP(F10, F11, F12, F13, ACTOF(s0 + 5))
        STEP(F20, F21, F22, F23, ACTOF(s0 + 6))
        STEP(F30, F31, F32, F33, ACTOF(s0 + 7))
        RENORM
    }
#undef STEP
#undef RENORM
#undef ACTOF

    // ---- stores
    if (isF) {
        *reinterpret_cast<f32x4*>(&beta_f[(size_t)(b0 + c) * NTAGS +  0 + 4 * g]) = P0;
        *reinterpret_cast<f32x4*>(&beta_f[(size_t)(b0 + c) * NTAGS + 16 + 4 * g]) = P1;
        *reinterpret_cast<f32x4*>(&beta_f[(size_t)(b0 + c) * NTAGS + 32 + 4 * g]) = P2;
        *reinterpret_cast<f32x4*>(&beta_f[(size_t)(b0 + c) * NTAGS + 48 + 4 * g]) = P3;
        if (g == 0) {
            Mf[b0 + c] = fmaf((float)LactF, LOGD, M);
            Lw[b0 + c] = Lc;
        }
    } else {
        *reinterpret_cast<f32x4*>(&gma[(size_t)(b0 + c) * NTAGS +  0 + 4 * g]) = P0;
        *reinterpret_cast<f32x4*>(&gma[(size_t)(b0 + c) * NTAGS + 16 + 4 * g]) = P1;
        *reinterpret_cast<f32x4*>(&gma[(size_t)(b0 + c) * NTAGS + 32 + 4 * g]) = P2;
        *reinterpret_cast<f32x4*>(&gma[(size_t)(b0 + c) * NTAGS + 48 + 4 * g]) = P3;
        if (g == 0) {
            int nb = max(Lc - 512, 0);
            Mb[b0 + c] = fmaf((float)nb, LOGD, M);
        }
    }
}

// Join: per chain, numerator (fully parallel masked gather-sum) + the
// midpoint dot Z = log(sum_j beta_j * B_j) + Mf + Mb; accumulate llh.
// (Verbatim from the verified R0 kernel.)
__global__ __launch_bounds__(64)
void join_kernel(const float* __restrict__ em,
                 const int* __restrict__ tags,
                 const float* __restrict__ startT,
                 const float* __restrict__ endT,
                 const float* __restrict__ trans,
                 const float* __restrict__ beta_f, const float* __restrict__ Mf,
                 const float* __restrict__ gma,    const float* __restrict__ Mb,
                 const int* __restrict__ Lw,
                 float* __restrict__ out)
{
    const int b = blockIdx.x;
    const int j = threadIdx.x;

    __shared__ float tr_sh[NTAGS * NTAGS];
#pragma unroll
    for (int i = 0; i < NTAGS; ++i)
        tr_sh[i * NTAGS + j] = trans[i * NTAGS + j];
    __syncthreads();

    const int L = Lw[b];

    float np = 0.0f;
#pragma unroll
    for (int k = 0; k < SEQ / 64; ++k) {
        int t = k * 64 + j;
        if (t >= 1 && t < L) {
            int ct = tags[t * BATCH + b];
            int pt = tags[(t - 1) * BATCH + b];
            np += tr_sh[pt * NTAGS + ct] + em[((size_t)t * BATCH + b) * NTAGS + ct];
        }
    }
    if (j == 0) {
        int t0 = tags[b];
        np += startT[t0] + em[(size_t)b * NTAGS + t0]
            + endT[tags[(size_t)(L - 1) * BATCH + b]];
    }

    float p = beta_f[b * NTAGS + j] * gma[b * NTAGS + j];

#pragma unroll
    for (int off = 32; off > 0; off >>= 1) {
        np += __shfl_xor(np, off);
        p  += __shfl_xor(p,  off);
    }

    if (j == 0) {
        float denom = __logf(p) + Mf[b] + Mb[b];
        atomicAdd(out, np - denom);
    }
}

extern "C" void kernel_launch(void* const* d_in, const int* in_sizes, int n_in,
                              void* d_out, int out_size, void* d_ws, size_t ws_size,
                              hipStream_t stream)
{
    const float* em     = (const float*)d_in[0];
    const int*   tags   = (const int*)d_in[1];
    const int*   mask   = (const int*)d_in[2];
    const float* startT = (const float*)d_in[3];
    const float* endT   = (const float*)d_in[4];
    const float* trans  = (const float*)d_in[5];
    float*       out    = (float*)d_out;

    float* beta_f = (float*)d_ws;                 // 512*64
    float* Mf     = beta_f + BATCH * NTAGS;       // 512
    float* gma    = Mf + BATCH;                   // 512*64
    float* Mb     = gma + BATCH * NTAGS;          // 512
    int*   Lw     = (int*)(Mb + BATCH);           // 512

    hipMemsetAsync(out, 0, sizeof(float) * out_size, stream);
    scan_kernel<<<2 * (BATCH / 16), 64, 0, stream>>>(em, mask, startT, endT, trans,
                                                     beta_f, Mf, gma, Mb, Lw);
    join_kernel<<<BATCH, 64, 0, stream>>>(em, tags, startT, endT, trans,
                                          beta_f, Mf, gma, Mb, Lw, out);
}